// Round 7
// baseline (352.441 us; speedup 1.0000x reference)
//
#include <hip/hip_runtime.h>

// GraphConstruction: x[1,1024,1024] fp32 -> A[4096,4096] in {0,1} fp32.
// patches[n,r,k] = x[h,w], h = (n&15)*64 + (r>>2)*16 + (n>>8),
//                          w = (r&3)*256 + k*16 + ((n>>4)&15)
// LOCKED NUMERICS (R6..R19, absmax 0):
//   sq[n,k]: acc = p0^2; acc = acc + fl(p_r^2), r ascending (plain adds)
//   G: acc = fmaf(a_r, b_r, acc), r ascending;  d2 = fmaf(-2,G,fl(si+sj))
//   decision: all_k (d2 <= 49.0f) == !any_k (d2 > 49.0f) -> per-cell FAIL
//   BIT. A bit-exactly symmetric -> mirror stores (duplicate identical
//   writes benign).
// R20: 512 threads (8 waves, intra-block residency proven in R19: Occ 16%),
//   128x256 tile, 8x8/thread (1.0 B/FMA), fixing R19's three failures:
//   (a) spill at 128-budget: amdgpu_num_vgpr(256)+waves_per_eu(2,2) pins
//       the budget (2 waves/SIMD x 256 = 512 regs = whole file; a 512-thr
//       block forces >=2 waves/EU, so min=2 is feasible). Live ~150.
//   (b) 4-way b-read conflicts (5.1e6 cyc): thread map ty=tid&15,
//       tx=tid>>4 -> wave's b-reads = 4 consecutive-tx rows (distinct
//       slots, conflict-free), a-reads 16 rows 2-way (free, m136).
//   (c) tail: tiles I>=2J = 256 full + 16 diagonal = 272 blocks. Full
//       tiles first (1 clean round on 256 CUs); diag tiles last with
//       triangular skip (active = i0+8ty+7 >= j0+8tx; waves 4-7 fully
//       inactive -> execz skip) ~0.6x cost.
//   Coverage: lower cells via home-tile direct (I>=2J always); upper
//   cells via mirror of (active) partner thread. LDS 58.4KB.

#define NPATCH 4096
#define BM 128
#define BN 256
#define NPH 8
#define KC 2
#define RSTRIDE 9          // float4 per row (8 data chunks + 1 pad)

__device__ __forceinline__ int swzrow(int row) {
    return ((row >> 2) + (row >> 5)) & 7;
}

// d{u}A holds cols v=0..3, d{u}B cols v=4..7; chain = fmaf r ascending.
#define FMA4(dst, av, bv)              \
    dst = fmaf(av.x, bv.x, dst);       \
    dst = fmaf(av.y, bv.y, dst);       \
    dst = fmaf(av.z, bv.z, dst);       \
    dst = fmaf(av.w, bv.w, dst);

#define LDA(u)                                                                 \
    const float4 a##u = Si[(ty * 8 + u) * RSTRIDE +                            \
                           (c ^ swzrow(ty * 8 + u))];

#define COL(v, comp)                                                           \
    {                                                                          \
        const int row_ = tx * 8 + v;                                           \
        const float4 b_ = Sj[row_ * RSTRIDE + (c ^ swzrow(row_))];             \
        FMA4(d0##comp, a0, b_)                                                 \
        FMA4(d1##comp, a1, b_)                                                 \
        FMA4(d2##comp, a2, b_)                                                 \
        FMA4(d3##comp, a3, b_)                                                 \
        FMA4(d4##comp, a4, b_)                                                 \
        FMA4(d5##comp, a5, b_)                                                 \
        FMA4(d6##comp, a6, b_)                                                 \
        FMA4(d7##comp, a7, b_)                                                 \
    }

#define CELL(dcomp, siv, sjv, fw, bit)                                         \
    {                                                                          \
        const float s_ = (siv) + (sjv);           /* fl(si+sj) */              \
        const float d2_ = fmaf(-2.0f, dcomp, s_); /* fl(s-2G)  */              \
        fw |= (d2_ > 49.0f ? 1u : 0u) << (bit);                                \
    }

#define EPIROW(u, siv, fw, base)                                               \
    CELL(d##u##A.x, siv, sj0.x, fw, (base) + 0)                                \
    CELL(d##u##A.y, siv, sj0.y, fw, (base) + 1)                                \
    CELL(d##u##A.z, siv, sj0.z, fw, (base) + 2)                                \
    CELL(d##u##A.w, siv, sj0.w, fw, (base) + 3)                                \
    CELL(d##u##B.x, siv, sj1.x, fw, (base) + 4)                                \
    CELL(d##u##B.y, siv, sj1.y, fw, (base) + 5)                                \
    CELL(d##u##B.z, siv, sj1.z, fw, (base) + 6)                                \
    CELL(d##u##B.w, siv, sj1.w, fw, (base) + 7)

__global__ __launch_bounds__(512)
__attribute__((amdgpu_waves_per_eu(2, 2), amdgpu_num_vgpr(256)))
void adj_kernel(const float* __restrict__ x, float* __restrict__ A) {
#pragma clang fp contract(off)
    __shared__ float4 Si[BM * RSTRIDE];
    __shared__ float4 Sj[BN * RSTRIDE];
    __shared__ float sqi[KC][BM];
    __shared__ float sqj[KC][BN];

    // blockIdx -> tile (I rows of 128, J cols of 256), I >= 2J.
    // Non-diag (I > 2J): t in [0,256), cum(J) = J*(32-J). Diag: t-256 -> J.
    int t = blockIdx.x;
    int I, J;
    if (t >= 256) {
        J = t - 256;
        I = 2 * J;
    } else {
        int Jf = (int)(16.0f - sqrtf(256.0f - (float)t));
        if (Jf < 0) Jf = 0;
        while ((Jf + 1) * (32 - (Jf + 1)) <= t) ++Jf;
        while (Jf * (32 - Jf) > t) --Jf;
        J = Jf;
        I = 2 * J + 1 + (t - J * (32 - J));
    }
    const int i0 = I * BM;
    const int j0 = J * BN;
    const int tid = threadIdx.x;
    const int ty = tid & 15;       // i-rows ty*8..+7   (fast index)
    const int tx = tid >> 4;       // j-cols tx*8..+7   (slow index)
    const bool active = (i0 + ty * 8 + 7) >= (j0 + tx * 8);

    unsigned fail0 = 0u, fail1 = 0u;   // bit u*8+v (u<4) / (u-4)*8+v

    for (int kp = 0; kp < NPH; ++kp) {
        __syncthreads();
        // ---- stage: 3072 float4 loads, 6/thread; each covers 4 rows ----
#pragma unroll
        for (int l = 0; l < 6; ++l) {
            int gid = l * 512 + tid;
            float* Sb;
            int h, w0, c, e, row0;
            if (gid < 1024) {              // Si: g(1)|kl(1)|r(4)|m4(4)
                int q = gid;
                int g = q & 1;
                int kl = (q >> 1) & 1;
                int r = (q >> 2) & 15;
                int m4 = q >> 6;
                int k = kp * KC + kl;
                h = m4 * 64 + (r >> 2) * 16 + (I >> 1);
                w0 = (r & 3) * 256 + k * 16 + 8 * (I & 1) + 4 * g;
                c = (kl << 2) | (r >> 2);
                e = r & 3;
                row0 = g * 64 + m4;        // row(dd) = row0 + 16*dd
                Sb = (float*)Si;
            } else {                       // Sj: G(2)|kl(1)|r(4)|m4(4)
                int q = gid - 1024;
                int G = q & 3;
                int kl = (q >> 2) & 1;
                int r = (q >> 3) & 15;
                int m4 = q >> 7;
                int k = kp * KC + kl;
                h = m4 * 64 + (r >> 2) * 16 + J;
                w0 = (r & 3) * 256 + k * 16 + 4 * G;
                c = (kl << 2) | (r >> 2);
                e = r & 3;
                row0 = G * 64 + m4;
                Sb = (float*)Sj;
            }
            float4 v = *(const float4*)&x[h * 1024 + w0];
#pragma unroll
            for (int dd = 0; dd < 4; ++dd) {
                float val = (dd == 0) ? v.x : (dd == 1) ? v.y : (dd == 2) ? v.z : v.w;
                int row = row0 + dd * 16;
                int ch = c ^ swzrow(row);
                Sb[(row * RSTRIDE + ch) * 4 + e] = val;
            }
        }
        __syncthreads();
        // ---- per-column sq: plain adds, r ascending; 768 values ----
#pragma unroll
        for (int s = 0; s < 2; ++s) {
            int idx = s * 512 + tid;
            if (idx < 768) {
                const float4* Sb;
                float* out;
                int row, kl;
                if (idx < 256) {
                    kl = idx >> 7;
                    row = idx & 127;
                    Sb = Si + row * RSTRIDE;
                    out = &sqi[kl][row];
                } else {
                    int e2 = idx - 256;
                    kl = e2 >> 8;
                    row = e2 & 255;
                    Sb = Sj + row * RSTRIDE;
                    out = &sqj[kl][row];
                }
                int swz = swzrow(row);
                float acc;
                {
                    float4 v = Sb[(kl * 4) ^ swz];
                    acc = v.x * v.x;
                    float t1 = v.y * v.y; acc = acc + t1;
                    float t2 = v.z * v.z; acc = acc + t2;
                    float t3 = v.w * v.w; acc = acc + t3;
                }
#pragma unroll
                for (int rc = 1; rc < 4; ++rc) {
                    float4 v = Sb[(kl * 4 + rc) ^ swz];
                    float t0 = v.x * v.x; acc = acc + t0;
                    float t1 = v.y * v.y; acc = acc + t1;
                    float t2 = v.z * v.z; acc = acc + t2;
                    float t3 = v.w * v.w; acc = acc + t3;
                }
                *out = acc;
            }
        }
        __syncthreads();
        // ---- compute: 8x8 cells via named float4 accumulators ----
        if (active) {
#pragma unroll
            for (int kl = 0; kl < KC; ++kl) {
                float4 d0A = {0.f, 0.f, 0.f, 0.f}, d0B = {0.f, 0.f, 0.f, 0.f};
                float4 d1A = {0.f, 0.f, 0.f, 0.f}, d1B = {0.f, 0.f, 0.f, 0.f};
                float4 d2A = {0.f, 0.f, 0.f, 0.f}, d2B = {0.f, 0.f, 0.f, 0.f};
                float4 d3A = {0.f, 0.f, 0.f, 0.f}, d3B = {0.f, 0.f, 0.f, 0.f};
                float4 d4A = {0.f, 0.f, 0.f, 0.f}, d4B = {0.f, 0.f, 0.f, 0.f};
                float4 d5A = {0.f, 0.f, 0.f, 0.f}, d5B = {0.f, 0.f, 0.f, 0.f};
                float4 d6A = {0.f, 0.f, 0.f, 0.f}, d6B = {0.f, 0.f, 0.f, 0.f};
                float4 d7A = {0.f, 0.f, 0.f, 0.f}, d7B = {0.f, 0.f, 0.f, 0.f};
#pragma unroll
                for (int rc = 0; rc < 4; ++rc) {
                    const int c = kl * 4 + rc;
                    LDA(0) LDA(1) LDA(2) LDA(3) LDA(4) LDA(5) LDA(6) LDA(7)
                    COL(0, A.x)
                    COL(1, A.y)
                    COL(2, A.z)
                    COL(3, A.w)
                    COL(4, B.x)
                    COL(5, B.y)
                    COL(6, B.z)
                    COL(7, B.w)
                }
                const float4 si0 = *(const float4*)&sqi[kl][ty * 8];
                const float4 si1 = *(const float4*)&sqi[kl][ty * 8 + 4];
                const float4 sj0 = *(const float4*)&sqj[kl][tx * 8];
                const float4 sj1 = *(const float4*)&sqj[kl][tx * 8 + 4];
                EPIROW(0, si0.x, fail0, 0)
                EPIROW(1, si0.y, fail0, 8)
                EPIROW(2, si0.z, fail0, 16)
                EPIROW(3, si0.w, fail0, 24)
                EPIROW(4, si1.x, fail1, 0)
                EPIROW(5, si1.y, fail1, 8)
                EPIROW(6, si1.z, fail1, 16)
                EPIROW(7, si1.w, fail1, 24)
            }
        }
    }

    // ---- stores: direct + mirrored (all under active) ----
    if (active) {
#pragma unroll
        for (int u = 0; u < 8; ++u) {
            unsigned m8 = ((u < 4) ? (fail0 >> (u * 8)) : (fail1 >> ((u - 4) * 8))) & 0xffu;
            float4 o0, o1;
            o0.x = (m8 & 1u)   ? 0.0f : 1.0f;
            o0.y = (m8 & 2u)   ? 0.0f : 1.0f;
            o0.z = (m8 & 4u)   ? 0.0f : 1.0f;
            o0.w = (m8 & 8u)   ? 0.0f : 1.0f;
            o1.x = (m8 & 16u)  ? 0.0f : 1.0f;
            o1.y = (m8 & 32u)  ? 0.0f : 1.0f;
            o1.z = (m8 & 64u)  ? 0.0f : 1.0f;
            o1.w = (m8 & 128u) ? 0.0f : 1.0f;
            size_t base = (size_t)(i0 + ty * 8 + u) * NPATCH + j0 + tx * 8;
            *(float4*)&A[base] = o0;
            *(float4*)&A[base + 4] = o1;
        }
#pragma unroll
        for (int v = 0; v < 8; ++v) {
            float4 o0, o1;
            o0.x = ((fail0 >> (0 * 8 + v)) & 1u) ? 0.0f : 1.0f;
            o0.y = ((fail0 >> (1 * 8 + v)) & 1u) ? 0.0f : 1.0f;
            o0.z = ((fail0 >> (2 * 8 + v)) & 1u) ? 0.0f : 1.0f;
            o0.w = ((fail0 >> (3 * 8 + v)) & 1u) ? 0.0f : 1.0f;
            o1.x = ((fail1 >> (0 * 8 + v)) & 1u) ? 0.0f : 1.0f;
            o1.y = ((fail1 >> (1 * 8 + v)) & 1u) ? 0.0f : 1.0f;
            o1.z = ((fail1 >> (2 * 8 + v)) & 1u) ? 0.0f : 1.0f;
            o1.w = ((fail1 >> (3 * 8 + v)) & 1u) ? 0.0f : 1.0f;
            size_t base = (size_t)(j0 + tx * 8 + v) * NPATCH + i0 + ty * 8;
            *(float4*)&A[base] = o0;
            *(float4*)&A[base + 4] = o1;
        }
    }
}

extern "C" void kernel_launch(void* const* d_in, const int* in_sizes, int n_in,
                              void* d_out, int out_size, void* d_ws, size_t ws_size,
                              hipStream_t stream) {
    const float* x = (const float*)d_in[0];
    float* A = (float*)d_out;
    (void)d_ws; (void)ws_size;

    const int nblk = 272;  // 256 full tiles + 16 diagonal tiles (last)
    adj_kernel<<<nblk, 512, 0, stream>>>(x, A);
}